// Round 4
// baseline (553.251 us; speedup 1.0000x reference)
//
#include <hip/hip_runtime.h>

#define N_NODES 10000
#define N_EDGES 30000
#define DIN     64
#define EDIM    16
#define H1      128
#define H2      64
#define C_OUT   10
#define NB      512     // grid size; 2 blocks/CU guaranteed resident

typedef __bf16 bfrag __attribute__((ext_vector_type(8)));
typedef float  f32x4 __attribute__((ext_vector_type(4)));

__device__ __forceinline__ ushort f2bf(float f) {
    union { float f; unsigned u; } x; x.f = f;
    unsigned r = x.u + 0x7fffu + ((x.u >> 16) & 1u);   // RNE; inputs finite
    return (ushort)(r >> 16);
}
__device__ __forceinline__ float bf2f(ushort s) {
    union { unsigned u; float f; } x; x.u = ((unsigned)s) << 16;
    return x.f;
}

// Grid-wide barrier. bar[0]=arrival (monotonic), bar[1]=release epoch.
// Requires all NB blocks co-resident (launch_bounds caps VGPR at 256 ->
// 2 waves/SIMD; LDS 35KB -> 4 blocks/CU; grid=512=2/CU: safe).
__device__ __forceinline__ void grid_sync(unsigned* bar, unsigned epoch) {
    __syncthreads();
    if (threadIdx.x == 0) {
        __threadfence();   // release: wbL2 so other XCDs see our writes
        unsigned prev = atomicAdd(&bar[0], 1u);
        if (prev == epoch * NB + (NB - 1)) {
            __hip_atomic_store(&bar[1], epoch + 1, __ATOMIC_RELEASE,
                               __HIP_MEMORY_SCOPE_AGENT);
        } else {
            while (__hip_atomic_load(&bar[1], __ATOMIC_ACQUIRE,
                                     __HIP_MEMORY_SCOPE_AGENT) < epoch + 1) {
                __builtin_amdgcn_s_sleep(16);
            }
        }
        __threadfence();   // acquire: invalidate L1/L2 so we see others' writes
    }
    __syncthreads();
}

__global__ __launch_bounds__(256, 2) void mega(
        const float* __restrict__ x, const float* __restrict__ ea,
        const int* __restrict__ src_idx, const int* __restrict__ dst_idx,
        const float* __restrict__ W1, const float* __restrict__ b1,
        const float* __restrict__ We1, const float* __restrict__ root1,
        const float* __restrict__ be1, const float* __restrict__ bias1,
        const float* __restrict__ We2, const float* __restrict__ be2,
        const float* __restrict__ root2, const float* __restrict__ bias2,
        ushort* __restrict__ h_bf, ushort* __restrict__ B1t,
        ushort* __restrict__ B2t, ushort* __restrict__ G1,
        float* __restrict__ hrb1, float* __restrict__ hb1,
        float* __restrict__ agg1, float* __restrict__ agg2,
        float* __restrict__ G2, float* __restrict__ hb2, float* __restrict__ hr2,
        float* __restrict__ out, unsigned* bar) {
    __shared__ float smem[DIN * H1 + H1 + 8 * DIN];   // 35.3 KB
    float* w_lds = smem;
    float* b_lds = smem + DIN * H1;
    float* x_lds = smem + DIN * H1 + H1;              // [8][DIN]
    int t = threadIdx.x;
    int bx = blockIdx.x;
    int gtid = bx * 256 + t;
    int wave = t >> 6, lane = t & 63;
    int quad = lane >> 4, lrow = lane & 15;

    // ========== P0: prep (B1t pack, B2t pack, zero agg, h=relu(x@W1+b1)) ====
    // B1t: [1152][128] bf16
    for (int idx = gtid; idx < 1152 * 128; idx += NB * 256) {
        int c = idx >> 7, i = idx & 127;
        float v;
        if (c < 1024)      v = We1[(size_t)(c >> 6) * (H1 * H2) + i * 64 + (c & 63)];
        else if (c < 1088) v = root1[i * 64 + (c - 1024)];
        else               v = be1[i * 64 + (c - 1088)];
        B1t[idx] = f2bf(v);
    }
    // B2t: [192][64] bf16 (cols 180..191 zero-pad)
    for (int idx = gtid; idx < 192 * 64; idx += NB * 256) {
        int c = idx >> 6, j = idx & 63;
        float v = 0.f;
        if (c < 160)      v = We2[(size_t)(c / 10) * 640 + j * 10 + (c % 10)];
        else if (c < 170) v = be2[j * 10 + (c - 160)];
        else if (c < 180) v = root2[j * 10 + (c - 170)];
        B2t[idx] = f2bf(v);
    }
    // zero agg1 (640000) || agg2 (100000): contiguous 740000 floats
    for (int i = gtid; i < 185000; i += NB * 256)
        ((float4*)agg1)[i] = make_float4(0.f, 0.f, 0.f, 0.f);
    // h = relu(x@W1+b1), bf16. Stage W1+b1 once, x-tile per iter.
    for (int idx = t; idx < DIN * H1 / 4; idx += 256)
        ((float4*)w_lds)[idx] = ((const float4*)W1)[idx];
    if (t < H1) b_lds[t] = b1[t];
    for (int tile = bx; tile < 1250; tile += NB) {
        __syncthreads();   // guards w_lds first use + x_lds reuse
        int n0 = tile * 8;
        if (t < 128) {
            int row = t >> 4, c4 = t & 15;
            int n = n0 + row;
            float4 v = make_float4(0.f, 0.f, 0.f, 0.f);
            if (n < N_NODES) v = ((const float4*)(x + (size_t)n * DIN))[c4];
            ((float4*)(x_lds + row * DIN))[c4] = v;
        }
        __syncthreads();
        int nl = t >> 5;
        int o  = (t & 31) * 4;
        int n  = n0 + nl;
        float4 acc = *(const float4*)&b_lds[o];
        #pragma unroll 8
        for (int i = 0; i < DIN; ++i) {
            float xv = x_lds[nl * DIN + i];
            float4 w = *(const float4*)&w_lds[i * H1 + o];
            acc.x = fmaf(xv, w.x, acc.x);
            acc.y = fmaf(xv, w.y, acc.y);
            acc.z = fmaf(xv, w.z, acc.z);
            acc.w = fmaf(xv, w.w, acc.w);
        }
        if (n < N_NODES) {
            ushort4 s;
            s.x = f2bf(fmaxf(acc.x, 0.f));
            s.y = f2bf(fmaxf(acc.y, 0.f));
            s.z = f2bf(fmaxf(acc.z, 0.f));
            s.w = f2bf(fmaxf(acc.w, 0.f));
            *(ushort4*)&h_bf[(size_t)n * H1 + o] = s;
        }
    }
    grid_sync(bar, 0);

    // ========== P1: GEMM C[10000x1152] = h_bf @ B1, tiles 128rows x 64cols ===
    for (int tile = bx; tile < 79 * 18; tile += NB) {
        int y = tile / 79;
        int mx = tile - y * 79;
        int nbase = mx * 128 + wave * 32;
        int ar0 = nbase + lrow;       if (ar0 > N_NODES - 1) ar0 = N_NODES - 1;
        int ar1 = nbase + 16 + lrow;  if (ar1 > N_NODES - 1) ar1 = N_NODES - 1;
        const ushort* bbase = B1t + (size_t)y * 64 * 128;
        f32x4 acc0[4] = {}, acc1[4] = {};
        #pragma unroll
        for (int kc = 0; kc < 128; kc += 32) {
            bfrag a0 = *reinterpret_cast<const bfrag*>(h_bf + (size_t)ar0 * 128 + kc + quad * 8);
            bfrag a1 = *reinterpret_cast<const bfrag*>(h_bf + (size_t)ar1 * 128 + kc + quad * 8);
            #pragma unroll
            for (int ct = 0; ct < 4; ++ct) {
                bfrag b = *reinterpret_cast<const bfrag*>(
                    bbase + (size_t)(ct * 16 + lrow) * 128 + kc + quad * 8);
                acc0[ct] = __builtin_amdgcn_mfma_f32_16x16x32_bf16(a0, b, acc0[ct], 0, 0, 0);
                acc1[ct] = __builtin_amdgcn_mfma_f32_16x16x32_bf16(a1, b, acc1[ct], 0, 0, 0);
            }
        }
        #pragma unroll
        for (int half = 0; half < 2; ++half) {
            int rbase = nbase + half * 16 + quad * 4;
            #pragma unroll
            for (int ct = 0; ct < 4; ++ct) {
                int col = ct * 16 + lrow;
                f32x4 a = half ? acc1[ct] : acc0[ct];
                #pragma unroll
                for (int r = 0; r < 4; ++r) {
                    int n = rbase + r;
                    if (n >= N_NODES) continue;
                    float v = a[r];
                    if (y < 16) {
                        G1[(size_t)n * 1024 + y * 64 + col] = f2bf(v);
                    } else if (y == 16) {
                        hrb1[(size_t)n * 64 + col] = v + bias1[col];
                    } else {
                        hb1[(size_t)n * 64 + col] = v;
                    }
                }
            }
        }
    }
    grid_sync(bar, 1);

    // ========== P2: edge pass 1 (wave per edge, lane = output o) ============
    for (int e = bx * 4 + wave; e < N_EDGES; e += NB * 4) {
        int s = src_idx[e], d = dst_idx[e];
        int o = lane;
        float m = hb1[(size_t)s * 64 + o];
        const ushort* g = G1 + (size_t)s * 1024 + o;
        const float* a = ea + (size_t)e * 16;
        #pragma unroll
        for (int k = 0; k < 16; ++k) m = fmaf(a[k], bf2f(g[k * 64]), m);
        atomicAdd(&agg1[(size_t)d * 64 + o], m);
    }
    grid_sync(bar, 2);

    // ========== P3: layer-2 GEMM, A = relu(agg1+hrb1) inline ================
    for (int tile = bx; tile < 157 * 3; tile += NB) {
        int y = tile / 157;
        int mx = tile - y * 157;
        int n0 = mx * 64 + wave * 16;
        int arow = n0 + lrow; if (arow > N_NODES - 1) arow = N_NODES - 1;
        f32x4 acc[4] = {};
        #pragma unroll
        for (int kc = 0; kc < 64; kc += 32) {
            size_t off = (size_t)arow * 64 + kc + quad * 8;
            f32x4 p0 = *(const f32x4*)(agg1 + off);
            f32x4 p1 = *(const f32x4*)(agg1 + off + 4);
            f32x4 q0 = *(const f32x4*)(hrb1 + off);
            f32x4 q1 = *(const f32x4*)(hrb1 + off + 4);
            bfrag a;
            #pragma unroll
            for (int j = 0; j < 4; ++j) {
                a[j]     = (__bf16)fmaxf(p0[j] + q0[j], 0.f);
                a[j + 4] = (__bf16)fmaxf(p1[j] + q1[j], 0.f);
            }
            #pragma unroll
            for (int ct = 0; ct < 4; ++ct) {
                bfrag b = *reinterpret_cast<const bfrag*>(
                    B2t + (size_t)(y * 64 + ct * 16 + lrow) * 64 + kc + quad * 8);
                acc[ct] = __builtin_amdgcn_mfma_f32_16x16x32_bf16(a, b, acc[ct], 0, 0, 0);
            }
        }
        #pragma unroll
        for (int ct = 0; ct < 4; ++ct) {
            int cg = y * 64 + ct * 16 + lrow;
            #pragma unroll
            for (int r = 0; r < 4; ++r) {
                int n = n0 + quad * 4 + r;
                if (n >= N_NODES) continue;
                float v = acc[ct][r];
                if (cg < 160)      G2[(size_t)n * 160 + cg] = v;
                else if (cg < 170) hb2[(size_t)n * 10 + (cg - 160)] = v;
                else if (cg < 180) hr2[(size_t)n * 10 + (cg - 170)] = v + bias2[cg - 170];
            }
        }
    }
    grid_sync(bar, 3);

    // ========== P4: edge pass 2 (thread per edge) ===========================
    for (int e = gtid; e < N_EDGES; e += NB * 256) {
        int s = src_idx[e], d = dst_idx[e];
        float msg[10];
        #pragma unroll
        for (int c = 0; c < 10; ++c) msg[c] = hb2[(size_t)s * 10 + c];
        const float* a = ea + (size_t)e * 16;
        const float* g = G2 + (size_t)s * 160;
        #pragma unroll
        for (int k = 0; k < 16; ++k) {
            float av = a[k];
            #pragma unroll
            for (int c = 0; c < 10; ++c) msg[c] = fmaf(av, g[k * 10 + c], msg[c]);
        }
        #pragma unroll
        for (int c = 0; c < 10; ++c) atomicAdd(&agg2[(size_t)d * 10 + c], msg[c]);
    }
    grid_sync(bar, 4);

    // ========== P5: log_softmax(agg2 + hr2) =================================
    for (int n = gtid; n < N_NODES; n += NB * 256) {
        float z[10]; float m = -1e30f;
        #pragma unroll
        for (int c = 0; c < 10; ++c) {
            z[c] = agg2[(size_t)n * 10 + c] + hr2[(size_t)n * 10 + c];
            m = fmaxf(m, z[c]);
        }
        float s = 0.f;
        #pragma unroll
        for (int c = 0; c < 10; ++c) s += expf(z[c] - m);
        float ls = logf(s);
        #pragma unroll
        for (int c = 0; c < 10; ++c) out[(size_t)n * 10 + c] = z[c] - m - ls;
    }
}

// ---------------------------------------------------------------------------
extern "C" void kernel_launch(void* const* d_in, const int* in_sizes, int n_in,
                              void* d_out, int out_size, void* d_ws, size_t ws_size,
                              hipStream_t stream) {
    const float* x     = (const float*)d_in[0];
    const float* ea    = (const float*)d_in[1];
    const int*   eidx  = (const int*)d_in[2];
    const float* W1    = (const float*)d_in[3];
    const float* b1    = (const float*)d_in[4];
    const float* We1   = (const float*)d_in[5];
    const float* be1   = (const float*)d_in[6];
    const float* root1 = (const float*)d_in[7];
    const float* bias1 = (const float*)d_in[8];
    const float* We2   = (const float*)d_in[9];
    const float* be2   = (const float*)d_in[10];
    const float* root2 = (const float*)d_in[11];
    const float* bias2 = (const float*)d_in[12];
    float* out = (float*)d_out;

    // workspace layout (float units, 16B-aligned)
    float* ws = (float*)d_ws;
    ushort* h_bf = (ushort*)ws;                        // 1,280,000 us = 640,000 f
    ushort* B1t  = (ushort*)(ws + 640000);             // 147,456 us -> 73,728 f
    ushort* B2t  = (ushort*)(ws + 713728);             // 12,288 us -> 6,144 f
    ushort* G1   = (ushort*)(ws + 719872);             // 10,240,000 us -> 5,120,000 f
    float* hrb1 = ws + 719872 + 5120000;               // 640,000
    float* hb1  = hrb1 + 640000;                       // 640,000
    float* agg1 = hb1  + 640000;                       // 640,000 (contiguous w/ agg2)
    float* agg2 = agg1 + 640000;                       // 100,000
    float* G2   = agg2 + 100000;                       // 1,600,000
    float* hb2  = G2   + 1600000;                      // 100,000
    float* hr2  = hb2  + 100000;                       // 100,000
    unsigned* bar = (unsigned*)(hr2 + 100000);         // 2 words

    hipMemsetAsync(bar, 0, 2 * sizeof(unsigned), stream);
    mega<<<NB, 256, 0, stream>>>(x, ea, eidx, eidx + N_EDGES,
                                 W1, b1, We1, root1, be1, bias1,
                                 We2, be2, root2, bias2,
                                 h_bf, B1t, B2t, G1, hrb1, hb1,
                                 agg1, agg2, G2, hb2, hr2, out, bar);
}

// Round 5
// 201.728 us; speedup vs baseline: 2.7426x; 2.7426x over previous
//
#include <hip/hip_runtime.h>

#define N_NODES 10000
#define N_EDGES 30000
#define DIN     64
#define EDIM    16
#define H1      128
#define H2      64
#define C_OUT   10

typedef __bf16 bfrag __attribute__((ext_vector_type(8)));
typedef float  f32x4 __attribute__((ext_vector_type(4)));
typedef ushort ushort8 __attribute__((ext_vector_type(8)));

__device__ __forceinline__ ushort f2bf(float f) {
    union { float f; unsigned u; } x; x.f = f;
    unsigned r = x.u + 0x7fffu + ((x.u >> 16) & 1u);   // RNE; inputs finite
    return (ushort)(r >> 16);
}
__device__ __forceinline__ float bf2f(ushort s) {
    union { unsigned u; float f; } x; x.u = ((unsigned)s) << 16;
    return x.f;
}

// ---------------------------------------------------------------------------
// kA: multi-role prep kernel (block-uniform branch):
//   blocks [0,1250):      h = relu(x@W1+b1) -> bf16
//   blocks [1250,1826):   pack B1t[1152][128] bf16 (We1 cols, root1, be1)
//   blocks [1826,1874):   pack B2t[192][64]  bf16 (We2 cols, be2, root2, pad 0)
//   blocks [1874,2055):   zero agg1||agg2 (740000 floats contiguous)
#define KA_B1   1250
#define KA_B2   (KA_B1 + 576)
#define KA_B3   (KA_B2 + 48)
#define KA_B4   (KA_B3 + 181)
__global__ __launch_bounds__(256) void kA_prep(
        const float* __restrict__ x, const float* __restrict__ W1,
        const float* __restrict__ b1,
        const float* __restrict__ We1, const float* __restrict__ root1,
        const float* __restrict__ be1,
        const float* __restrict__ We2, const float* __restrict__ be2,
        const float* __restrict__ root2,
        ushort* __restrict__ h_bf, ushort* __restrict__ B1t,
        ushort* __restrict__ B2t, float* __restrict__ aggz) {
    int t = threadIdx.x;
    int bx = blockIdx.x;
    if (bx < KA_B1) {
        __shared__ float w_lds[DIN * H1];
        __shared__ float b_lds[H1];
        __shared__ float x_lds[8][DIN];
        for (int idx = t; idx < DIN * H1 / 4; idx += 256)
            ((float4*)w_lds)[idx] = ((const float4*)W1)[idx];
        if (t < H1) b_lds[t] = b1[t];
        int n0 = bx * 8;
        if (t < 128) {
            int row = t >> 4, c4 = t & 15;
            int n = n0 + row;
            float4 v = make_float4(0.f, 0.f, 0.f, 0.f);
            if (n < N_NODES) v = ((const float4*)(x + (size_t)n * DIN))[c4];
            ((float4*)(x_lds[row]))[c4] = v;
        }
        __syncthreads();
        int nl = t >> 5;
        int o  = (t & 31) * 4;
        int n  = n0 + nl;
        float4 acc = *(const float4*)&b_lds[o];
        #pragma unroll 8
        for (int i = 0; i < DIN; ++i) {
            float xv = x_lds[nl][i];
            float4 w = *(const float4*)&w_lds[i * H1 + o];
            acc.x = fmaf(xv, w.x, acc.x);
            acc.y = fmaf(xv, w.y, acc.y);
            acc.z = fmaf(xv, w.z, acc.z);
            acc.w = fmaf(xv, w.w, acc.w);
        }
        if (n < N_NODES) {
            ushort4 s;
            s.x = f2bf(fmaxf(acc.x, 0.f));
            s.y = f2bf(fmaxf(acc.y, 0.f));
            s.z = f2bf(fmaxf(acc.z, 0.f));
            s.w = f2bf(fmaxf(acc.w, 0.f));
            *(ushort4*)&h_bf[(size_t)n * H1 + o] = s;
        }
    } else if (bx < KA_B2) {
        int idx = (bx - KA_B1) * 256 + t;
        int c = idx >> 7, i = idx & 127;
        float v;
        if (c < 1024)      v = We1[(size_t)(c >> 6) * (H1 * H2) + i * 64 + (c & 63)];
        else if (c < 1088) v = root1[i * 64 + (c - 1024)];
        else               v = be1[i * 64 + (c - 1088)];
        B1t[idx] = f2bf(v);
    } else if (bx < KA_B3) {
        int idx = (bx - KA_B2) * 256 + t;
        int c = idx >> 6, j = idx & 63;
        float v = 0.f;
        if (c < 160)      v = We2[(size_t)(c / 10) * 640 + j * 10 + (c % 10)];
        else if (c < 170) v = be2[j * 10 + (c - 160)];
        else if (c < 180) v = root2[j * 10 + (c - 170)];
        B2t[idx] = f2bf(v);
    } else {
        int zb = bx - KA_B3;
        for (int i = zb * 256 + t; i < 185000; i += 181 * 256)
            ((float4*)aggz)[i] = make_float4(0.f, 0.f, 0.f, 0.f);
    }
}

// ---------------------------------------------------------------------------
// K3: bf16 MFMA GEMM  C[10000 x 1152] = h_bf[10000 x 128] @ B1[128 x 1152]
// grid.x = M-tiles of 128 (79), grid.y = col-blocks of 64 (18).
// wave = 32 rows x 64 cols (2 A-frags share each B-frag).
// Epilogue for y<16 writes TRANSPOSED G1t[n][o*16 + k] (k = y).
__global__ __launch_bounds__(256) void k3_mfma(
        const ushort* __restrict__ h_bf, const ushort* __restrict__ Bt,
        const float* __restrict__ bias1,
        ushort* __restrict__ G1t, float* __restrict__ hrb1, float* __restrict__ hb1) {
    int t = threadIdx.x;
    int wave = t >> 6, lane = t & 63;
    int quad = lane >> 4, lrow = lane & 15;
    int y = blockIdx.y;
    int nbase = blockIdx.x * 128 + wave * 32;
    int ar0 = nbase + lrow;       if (ar0 > N_NODES - 1) ar0 = N_NODES - 1;
    int ar1 = nbase + 16 + lrow;  if (ar1 > N_NODES - 1) ar1 = N_NODES - 1;
    const ushort* bbase = Bt + (size_t)y * 64 * 128;
    f32x4 acc0[4] = {}, acc1[4] = {};
    #pragma unroll
    for (int kc = 0; kc < 128; kc += 32) {
        bfrag a0 = *reinterpret_cast<const bfrag*>(h_bf + (size_t)ar0 * 128 + kc + quad * 8);
        bfrag a1 = *reinterpret_cast<const bfrag*>(h_bf + (size_t)ar1 * 128 + kc + quad * 8);
        #pragma unroll
        for (int ct = 0; ct < 4; ++ct) {
            bfrag b = *reinterpret_cast<const bfrag*>(
                bbase + (size_t)(ct * 16 + lrow) * 128 + kc + quad * 8);
            acc0[ct] = __builtin_amdgcn_mfma_f32_16x16x32_bf16(a0, b, acc0[ct], 0, 0, 0);
            acc1[ct] = __builtin_amdgcn_mfma_f32_16x16x32_bf16(a1, b, acc1[ct], 0, 0, 0);
        }
    }
    #pragma unroll
    for (int half = 0; half < 2; ++half) {
        int rbase = nbase + half * 16 + quad * 4;
        #pragma unroll
        for (int ct = 0; ct < 4; ++ct) {
            int col = ct * 16 + lrow;
            f32x4 a = half ? acc1[ct] : acc0[ct];
            #pragma unroll
            for (int r = 0; r < 4; ++r) {
                int n = rbase + r;
                if (n >= N_NODES) continue;
                float v = a[r];
                if (y < 16) {
                    // transposed: G1t[n][col][y]
                    G1t[(size_t)n * 1024 + col * 16 + y] = f2bf(v);
                } else if (y == 16) {
                    hrb1[(size_t)n * 64 + col] = v + bias1[col];
                } else {
                    hb1[(size_t)n * 64 + col] = v;
                }
            }
        }
    }
}

// ---------------------------------------------------------------------------
// K4: edge pass 1. wave per edge, lane = output o. G1t[n][o][k] bf16:
// lane reads 32 contiguous bytes (2 x 16B) instead of 16 x 2B.
__global__ __launch_bounds__(256) void k4_edge1(
        const float* __restrict__ ea, const int* __restrict__ src_idx,
        const int* __restrict__ dst_idx, const ushort* __restrict__ G1t,
        const float* __restrict__ hb1, float* __restrict__ agg1) {
    int t = threadIdx.x;
    int e = blockIdx.x * 4 + (t >> 6);
    int o = t & 63;
    int s = src_idx[e], d = dst_idx[e];
    float m = hb1[(size_t)s * 64 + o];
    const ushort* g = G1t + (size_t)s * 1024 + o * 16;
    ushort8 g0 = *reinterpret_cast<const ushort8*>(g);
    ushort8 g1 = *reinterpret_cast<const ushort8*>(g + 8);
    const float* a = ea + (size_t)e * 16;   // wave-uniform -> scalar loads
    #pragma unroll
    for (int k = 0; k < 8; ++k) m = fmaf(a[k], bf2f(g0[k]), m);
    #pragma unroll
    for (int k = 0; k < 8; ++k) m = fmaf(a[k + 8], bf2f(g1[k]), m);
    atomicAdd(&agg1[(size_t)d * 64 + o], m);
}

// ---------------------------------------------------------------------------
// K56: layer-2 node GEMM via MFMA, consuming relu(agg1+hrb1) inline.
//   C[10000 x 192] = relu(agg1+hrb1)[10000 x 64] @ B2[64 x 192]
// Epilogue: cg<160 -> TRANSPOSED G2t[n][c*16+k] (cg = k*10+c); 160..169 hb2;
//           170..179 hr2(+bias2); else drop.
__global__ __launch_bounds__(256) void k56_mfma(
        const float* __restrict__ agg1, const float* __restrict__ hrb1,
        const ushort* __restrict__ B2t, const float* __restrict__ bias2,
        float* __restrict__ G2t, float* __restrict__ hb2, float* __restrict__ hr2) {
    int t = threadIdx.x;
    int wave = t >> 6, lane = t & 63;
    int quad = lane >> 4, lrow = lane & 15;
    int y = blockIdx.y;
    int n0 = blockIdx.x * 64 + wave * 16;
    int arow = n0 + lrow; if (arow > N_NODES - 1) arow = N_NODES - 1;
    f32x4 acc[4] = {};
    #pragma unroll
    for (int kc = 0; kc < 64; kc += 32) {
        size_t off = (size_t)arow * 64 + kc + quad * 8;
        f32x4 p0 = *(const f32x4*)(agg1 + off);
        f32x4 p1 = *(const f32x4*)(agg1 + off + 4);
        f32x4 q0 = *(const f32x4*)(hrb1 + off);
        f32x4 q1 = *(const f32x4*)(hrb1 + off + 4);
        bfrag a;
        #pragma unroll
        for (int j = 0; j < 4; ++j) {
            a[j]     = (__bf16)fmaxf(p0[j] + q0[j], 0.f);
            a[j + 4] = (__bf16)fmaxf(p1[j] + q1[j], 0.f);
        }
        #pragma unroll
        for (int ct = 0; ct < 4; ++ct) {
            bfrag b = *reinterpret_cast<const bfrag*>(
                B2t + (size_t)(y * 64 + ct * 16 + lrow) * 64 + kc + quad * 8);
            acc[ct] = __builtin_amdgcn_mfma_f32_16x16x32_bf16(a, b, acc[ct], 0, 0, 0);
        }
    }
    #pragma unroll
    for (int ct = 0; ct < 4; ++ct) {
        int cg = y * 64 + ct * 16 + lrow;
        int kk = cg / 10, cc = cg - kk * 10;   // cg = kk*10 + cc
        #pragma unroll
        for (int r = 0; r < 4; ++r) {
            int n = n0 + quad * 4 + r;
            if (n >= N_NODES) continue;
            float v = acc[ct][r];
            if (cg < 160)      G2t[(size_t)n * 160 + cc * 16 + kk] = v;
            else if (cg < 170) hb2[(size_t)n * 10 + (cg - 160)] = v;
            else if (cg < 180) hr2[(size_t)n * 10 + (cg - 170)] = v + bias2[cg - 170];
        }
    }
}

// ---------------------------------------------------------------------------
// K7: edge pass 2. thread per (edge, class): 10 threads/edge.
// G2t[n][c][k]: each thread reads 16 contiguous floats (4 x dwordx4).
__global__ __launch_bounds__(256) void k7_edge2(
        const float* __restrict__ ea, const int* __restrict__ src_idx,
        const int* __restrict__ dst_idx, const float* __restrict__ G2t,
        const float* __restrict__ hb2, float* __restrict__ agg2) {
    int tid = blockIdx.x * 256 + threadIdx.x;
    if (tid >= N_EDGES * 10) return;
    int e = tid / 10, c = tid - e * 10;
    int s = src_idx[e], d = dst_idx[e];
    float m = hb2[(size_t)s * 10 + c];
    const float* g = G2t + (size_t)s * 160 + c * 16;
    const float* a = ea + (size_t)e * 16;
    f32x4 g0 = *(const f32x4*)g,       g1 = *(const f32x4*)(g + 4);
    f32x4 g2 = *(const f32x4*)(g + 8), g3 = *(const f32x4*)(g + 12);
    f32x4 a0 = *(const f32x4*)a,       a1 = *(const f32x4*)(a + 4);
    f32x4 a2 = *(const f32x4*)(a + 8), a3 = *(const f32x4*)(a + 12);
    #pragma unroll
    for (int k = 0; k < 4; ++k) {
        m = fmaf(a0[k], g0[k], m);
        m = fmaf(a1[k], g1[k], m);
        m = fmaf(a2[k], g2[k], m);
        m = fmaf(a3[k], g3[k], m);
    }
    atomicAdd(&agg2[(size_t)d * 10 + c], m);
}

// ---------------------------------------------------------------------------
// K8: z = agg2 + hr2; out = log_softmax(z)
__global__ void k8_logsoftmax(const float* __restrict__ agg2, const float* __restrict__ hr2,
                              float* __restrict__ out) {
    int n = blockIdx.x * blockDim.x + threadIdx.x;
    if (n >= N_NODES) return;
    float z[10]; float m = -1e30f;
    #pragma unroll
    for (int c = 0; c < 10; ++c) {
        z[c] = agg2[(size_t)n * 10 + c] + hr2[(size_t)n * 10 + c];
        m = fmaxf(m, z[c]);
    }
    float s = 0.f;
    #pragma unroll
    for (int c = 0; c < 10; ++c) s += expf(z[c] - m);
    float ls = logf(s);
    #pragma unroll
    for (int c = 0; c < 10; ++c) out[(size_t)n * 10 + c] = z[c] - m - ls;
}

// ---------------------------------------------------------------------------
extern "C" void kernel_launch(void* const* d_in, const int* in_sizes, int n_in,
                              void* d_out, int out_size, void* d_ws, size_t ws_size,
                              hipStream_t stream) {
    const float* x     = (const float*)d_in[0];
    const float* ea    = (const float*)d_in[1];
    const int*   eidx  = (const int*)d_in[2];
    const float* W1    = (const float*)d_in[3];
    const float* b1    = (const float*)d_in[4];
    const float* We1   = (const float*)d_in[5];
    const float* be1   = (const float*)d_in[6];
    const float* root1 = (const float*)d_in[7];
    const float* bias1 = (const float*)d_in[8];
    const float* We2   = (const float*)d_in[9];
    const float* be2   = (const float*)d_in[10];
    const float* root2 = (const float*)d_in[11];
    const float* bias2 = (const float*)d_in[12];
    float* out = (float*)d_out;

    // workspace layout (float units, all 16B-aligned)
    float* ws = (float*)d_ws;
    ushort* h_bf = (ushort*)ws;                        // 1,280,000 us = 640,000 f
    ushort* B1t  = (ushort*)(ws + 640000);             // 147,456 us -> 73,728 f
    ushort* B2t  = (ushort*)(ws + 713728);             // 12,288 us -> 6,144 f
    ushort* G1t  = (ushort*)(ws + 719872);             // 10,240,000 us -> 5,120,000 f
    float* hrb1 = ws + 719872 + 5120000;               // 640,000
    float* hb1  = hrb1 + 640000;                       // 640,000
    float* agg1 = hb1  + 640000;                       // 640,000  (contiguous with agg2)
    float* agg2 = agg1 + 640000;                       // 100,000
    float* G2t  = agg2 + 100000;                       // 1,600,000
    float* hb2  = G2t  + 1600000;                      // 100,000
    float* hr2  = hb2  + 100000;                       // 100,000

    kA_prep<<<KA_B4, 256, 0, stream>>>(x, W1, b1, We1, root1, be1, We2, be2, root2,
                                       h_bf, B1t, B2t, agg1);
    k3_mfma<<<dim3(79, 18), 256, 0, stream>>>(h_bf, B1t, bias1, G1t, hrb1, hb1);
    k4_edge1<<<7500, 256, 0, stream>>>(ea, eidx, eidx + N_EDGES, G1t, hb1, agg1);
    k56_mfma<<<dim3(157, 3), 256, 0, stream>>>(agg1, hrb1, B2t, bias2, G2t, hb2, hr2);
    k7_edge2<<<1172, 256, 0, stream>>>(ea, eidx, eidx + N_EDGES, G2t, hb2, agg2);
    k8_logsoftmax<<<40, 256, 0, stream>>>(agg2, hr2, out);
}

// Round 6
// 144.836 us; speedup vs baseline: 3.8198x; 1.3928x over previous
//
#include <hip/hip_runtime.h>

#define N_NODES 10000
#define N_EDGES 30000
#define DIN     64
#define EDIM    16
#define H1      128
#define H2      64
#define C_OUT   10

typedef __bf16 bfrag __attribute__((ext_vector_type(8)));
typedef float  f32x4 __attribute__((ext_vector_type(4)));
typedef ushort ushort8 __attribute__((ext_vector_type(8)));

__device__ __forceinline__ ushort f2bf(float f) {
    union { float f; unsigned u; } x; x.f = f;
    unsigned r = x.u + 0x7fffu + ((x.u >> 16) & 1u);   // RNE; inputs finite
    return (ushort)(r >> 16);
}
__device__ __forceinline__ float bf2f(ushort s) {
    union { unsigned u; float f; } x; x.u = ((unsigned)s) << 16;
    return x.f;
}

// ---------------------------------------------------------------------------
// kA: multi-role prep kernel (block-uniform branch):
//   blocks [0,1250):      h = relu(x@W1+b1) -> bf16
//   blocks [1250,1826):   pack B1t[1152][128] bf16 in PERMUTED col order:
//                         row c' = o*16+k <-> We1 col k*64+o  (c' < 1024)
//                         [1024,1088) root1 col, [1088,1152) be1 col
//   blocks [1826,1874):   pack B2t[192][64] bf16, row c' = c*16+k <-> We2 col
//                         k*10+c (c' < 160); [160,170) be2; [170,180) root2; pad
//   blocks [1874,2055):   zero agg1||agg2 (740000 floats contiguous)
#define KA_B1   1250
#define KA_B2   (KA_B1 + 576)
#define KA_B3   (KA_B2 + 48)
#define KA_B4   (KA_B3 + 181)
__global__ __launch_bounds__(256) void kA_prep(
        const float* __restrict__ x, const float* __restrict__ W1,
        const float* __restrict__ b1,
        const float* __restrict__ We1, const float* __restrict__ root1,
        const float* __restrict__ be1,
        const float* __restrict__ We2, const float* __restrict__ be2,
        const float* __restrict__ root2,
        ushort* __restrict__ h_bf, ushort* __restrict__ B1t,
        ushort* __restrict__ B2t, float* __restrict__ aggz) {
    int t = threadIdx.x;
    int bx = blockIdx.x;
    if (bx < KA_B1) {
        __shared__ float w_lds[DIN * H1];
        __shared__ float b_lds[H1];
        __shared__ float x_lds[8][DIN];
        for (int idx = t; idx < DIN * H1 / 4; idx += 256)
            ((float4*)w_lds)[idx] = ((const float4*)W1)[idx];
        if (t < H1) b_lds[t] = b1[t];
        int n0 = bx * 8;
        if (t < 128) {
            int row = t >> 4, c4 = t & 15;
            int n = n0 + row;
            float4 v = make_float4(0.f, 0.f, 0.f, 0.f);
            if (n < N_NODES) v = ((const float4*)(x + (size_t)n * DIN))[c4];
            ((float4*)(x_lds[row]))[c4] = v;
        }
        __syncthreads();
        int nl = t >> 5;
        int o  = (t & 31) * 4;
        int n  = n0 + nl;
        float4 acc = *(const float4*)&b_lds[o];
        #pragma unroll 8
        for (int i = 0; i < DIN; ++i) {
            float xv = x_lds[nl][i];
            float4 w = *(const float4*)&w_lds[i * H1 + o];
            acc.x = fmaf(xv, w.x, acc.x);
            acc.y = fmaf(xv, w.y, acc.y);
            acc.z = fmaf(xv, w.z, acc.z);
            acc.w = fmaf(xv, w.w, acc.w);
        }
        if (n < N_NODES) {
            ushort4 s;
            s.x = f2bf(fmaxf(acc.x, 0.f));
            s.y = f2bf(fmaxf(acc.y, 0.f));
            s.z = f2bf(fmaxf(acc.z, 0.f));
            s.w = f2bf(fmaxf(acc.w, 0.f));
            *(ushort4*)&h_bf[(size_t)n * H1 + o] = s;
        }
    } else if (bx < KA_B2) {
        int idx = (bx - KA_B1) * 256 + t;
        int c = idx >> 7, i = idx & 127;
        float v;
        if (c < 1024) {
            int o = c >> 4, k = c & 15;              // permuted: c' = o*16 + k
            v = We1[(size_t)k * (H1 * H2) + i * 64 + o];
        } else if (c < 1088) v = root1[i * 64 + (c - 1024)];
        else                 v = be1[i * 64 + (c - 1088)];
        B1t[idx] = f2bf(v);
    } else if (bx < KA_B3) {
        int idx = (bx - KA_B2) * 256 + t;
        int c = idx >> 6, j = idx & 63;
        float v = 0.f;
        if (c < 160) {
            int cc = c >> 4, k = c & 15;             // permuted: c' = cc*16 + k
            v = We2[(size_t)k * 640 + j * 10 + cc];
        }
        else if (c < 170) v = be2[j * 10 + (c - 160)];
        else if (c < 180) v = root2[j * 10 + (c - 170)];
        B2t[idx] = f2bf(v);
    } else {
        int zb = bx - KA_B3;
        for (int i = zb * 256 + t; i < 185000; i += 181 * 256)
            ((float4*)aggz)[i] = make_float4(0.f, 0.f, 0.f, 0.f);
    }
}

// ---------------------------------------------------------------------------
// K3: bf16 MFMA GEMM  C[10000 x 1152] = h_bf[10000 x 128] @ B1[128 x 1152]
// B1t rows are PERMUTED (c' = o*16+k), so the coalesced direct store of
// column-block y IS the G1t[n][o][k] layout k4 wants.
__global__ __launch_bounds__(256) void k3_mfma(
        const ushort* __restrict__ h_bf, const ushort* __restrict__ Bt,
        const float* __restrict__ bias1,
        ushort* __restrict__ G1t, float* __restrict__ hrb1, float* __restrict__ hb1) {
    int t = threadIdx.x;
    int wave = t >> 6, lane = t & 63;
    int quad = lane >> 4, lrow = lane & 15;
    int y = blockIdx.y;
    int nbase = blockIdx.x * 128 + wave * 32;
    int ar0 = nbase + lrow;       if (ar0 > N_NODES - 1) ar0 = N_NODES - 1;
    int ar1 = nbase + 16 + lrow;  if (ar1 > N_NODES - 1) ar1 = N_NODES - 1;
    const ushort* bbase = Bt + (size_t)y * 64 * 128;
    f32x4 acc0[4] = {}, acc1[4] = {};
    #pragma unroll
    for (int kc = 0; kc < 128; kc += 32) {
        bfrag a0 = *reinterpret_cast<const bfrag*>(h_bf + (size_t)ar0 * 128 + kc + quad * 8);
        bfrag a1 = *reinterpret_cast<const bfrag*>(h_bf + (size_t)ar1 * 128 + kc + quad * 8);
        #pragma unroll
        for (int ct = 0; ct < 4; ++ct) {
            bfrag b = *reinterpret_cast<const bfrag*>(
                bbase + (size_t)(ct * 16 + lrow) * 128 + kc + quad * 8);
            acc0[ct] = __builtin_amdgcn_mfma_f32_16x16x32_bf16(a0, b, acc0[ct], 0, 0, 0);
            acc1[ct] = __builtin_amdgcn_mfma_f32_16x16x32_bf16(a1, b, acc1[ct], 0, 0, 0);
        }
    }
    #pragma unroll
    for (int half = 0; half < 2; ++half) {
        int rbase = nbase + half * 16 + quad * 4;
        #pragma unroll
        for (int ct = 0; ct < 4; ++ct) {
            int col = ct * 16 + lrow;
            f32x4 a = half ? acc1[ct] : acc0[ct];
            #pragma unroll
            for (int r = 0; r < 4; ++r) {
                int n = rbase + r;
                if (n >= N_NODES) continue;
                float v = a[r];
                if (y < 16) {
                    G1t[(size_t)n * 1024 + y * 64 + col] = f2bf(v);  // coalesced
                } else if (y == 16) {
                    hrb1[(size_t)n * 64 + col] = v + bias1[col];
                } else {
                    hb1[(size_t)n * 64 + col] = v;
                }
            }
        }
    }
}

// ---------------------------------------------------------------------------
// K4: edge pass 1. wave per edge, lane = output o. G1t[n][o][k] bf16:
// lane reads 32 contiguous bytes (2 x 16B).
__global__ __launch_bounds__(256) void k4_edge1(
        const float* __restrict__ ea, const int* __restrict__ src_idx,
        const int* __restrict__ dst_idx, const ushort* __restrict__ G1t,
        const float* __restrict__ hb1, float* __restrict__ agg1) {
    int t = threadIdx.x;
    int e = blockIdx.x * 4 + (t >> 6);
    int o = t & 63;
    int s = src_idx[e], d = dst_idx[e];
    float m = hb1[(size_t)s * 64 + o];
    const ushort* g = G1t + (size_t)s * 1024 + o * 16;
    ushort8 g0 = *reinterpret_cast<const ushort8*>(g);
    ushort8 g1 = *reinterpret_cast<const ushort8*>(g + 8);
    const float* a = ea + (size_t)e * 16;   // wave-uniform -> scalar loads
    #pragma unroll
    for (int k = 0; k < 8; ++k) m = fmaf(a[k], bf2f(g0[k]), m);
    #pragma unroll
    for (int k = 0; k < 8; ++k) m = fmaf(a[k + 8], bf2f(g1[k]), m);
    atomicAdd(&agg1[(size_t)d * 64 + o], m);
}

// ---------------------------------------------------------------------------
// K56: layer-2 node GEMM via MFMA, A = relu(agg1+hrb1) inline.
// B2t rows permuted (c' = c*16+k) -> direct coalesced store is G2t[n][c][k].
//   cg in [160,170) -> hb2; [170,180) -> hr2(+bias2); else drop.
__global__ __launch_bounds__(256) void k56_mfma(
        const float* __restrict__ agg1, const float* __restrict__ hrb1,
        const ushort* __restrict__ B2t, const float* __restrict__ bias2,
        float* __restrict__ G2t, float* __restrict__ hb2, float* __restrict__ hr2) {
    int t = threadIdx.x;
    int wave = t >> 6, lane = t & 63;
    int quad = lane >> 4, lrow = lane & 15;
    int y = blockIdx.y;
    int n0 = blockIdx.x * 64 + wave * 16;
    int arow = n0 + lrow; if (arow > N_NODES - 1) arow = N_NODES - 1;
    f32x4 acc[4] = {};
    #pragma unroll
    for (int kc = 0; kc < 64; kc += 32) {
        size_t off = (size_t)arow * 64 + kc + quad * 8;
        f32x4 p0 = *(const f32x4*)(agg1 + off);
        f32x4 p1 = *(const f32x4*)(agg1 + off + 4);
        f32x4 q0 = *(const f32x4*)(hrb1 + off);
        f32x4 q1 = *(const f32x4*)(hrb1 + off + 4);
        bfrag a;
        #pragma unroll
        for (int j = 0; j < 4; ++j) {
            a[j]     = (__bf16)fmaxf(p0[j] + q0[j], 0.f);
            a[j + 4] = (__bf16)fmaxf(p1[j] + q1[j], 0.f);
        }
        #pragma unroll
        for (int ct = 0; ct < 4; ++ct) {
            bfrag b = *reinterpret_cast<const bfrag*>(
                B2t + (size_t)(y * 64 + ct * 16 + lrow) * 64 + kc + quad * 8);
            acc[ct] = __builtin_amdgcn_mfma_f32_16x16x32_bf16(a, b, acc[ct], 0, 0, 0);
        }
    }
    #pragma unroll
    for (int ct = 0; ct < 4; ++ct) {
        int cg = y * 64 + ct * 16 + lrow;
        #pragma unroll
        for (int r = 0; r < 4; ++r) {
            int n = n0 + quad * 4 + r;
            if (n >= N_NODES) continue;
            float v = acc[ct][r];
            if (cg < 160)      G2t[(size_t)n * 160 + cg] = v;   // coalesced
            else if (cg < 170) hb2[(size_t)n * 10 + (cg - 160)] = v;
            else if (cg < 180) hr2[(size_t)n * 10 + (cg - 170)] = v + bias2[cg - 170];
        }
    }
}

// ---------------------------------------------------------------------------
// K7: edge pass 2. thread per (edge, class): 10 threads/edge.
// G2t[n][c][k]: each thread reads 16 contiguous floats (4 x dwordx4).
__global__ __launch_bounds__(256) void k7_edge2(
        const float* __restrict__ ea, const int* __restrict__ src_idx,
        const int* __restrict__ dst_idx, const float* __restrict__ G2t,
        const float* __restrict__ hb2, float* __restrict__ agg2) {
    int tid = blockIdx.x * 256 + threadIdx.x;
    if (tid >= N_EDGES * 10) return;
    int e = tid / 10, c = tid - e * 10;
    int s = src_idx[e], d = dst_idx[e];
    float m = hb2[(size_t)s * 10 + c];
    const float* g = G2t + (size_t)s * 160 + c * 16;
    const float* a = ea + (size_t)e * 16;
    f32x4 g0 = *(const f32x4*)g,       g1 = *(const f32x4*)(g + 4);
    f32x4 g2 = *(const f32x4*)(g + 8), g3 = *(const f32x4*)(g + 12);
    f32x4 a0 = *(const f32x4*)a,       a1 = *(const f32x4*)(a + 4);
    f32x4 a2 = *(const f32x4*)(a + 8), a3 = *(const f32x4*)(a + 12);
    #pragma unroll
    for (int k = 0; k < 4; ++k) {
        m = fmaf(a0[k], g0[k], m);
        m = fmaf(a1[k], g1[k], m);
        m = fmaf(a2[k], g2[k], m);
        m = fmaf(a3[k], g3[k], m);
    }
    atomicAdd(&agg2[(size_t)d * 10 + c], m);
}

// ---------------------------------------------------------------------------
// K8: z = agg2 + hr2; out = log_softmax(z)
__global__ void k8_logsoftmax(const float* __restrict__ agg2, const float* __restrict__ hr2,
                              float* __restrict__ out) {
    int n = blockIdx.x * blockDim.x + threadIdx.x;
    if (n >= N_NODES) return;
    float z[10]; float m = -1e30f;
    #pragma unroll
    for (int c = 0; c < 10; ++c) {
        z[c] = agg2[(size_t)n * 10 + c] + hr2[(size_t)n * 10 + c];
        m = fmaxf(m, z[c]);
    }
    float s = 0.f;
    #pragma unroll
    for (int c = 0; c < 10; ++c) s += expf(z[c] - m);
    float ls = logf(s);
    #pragma unroll
    for (int c = 0; c < 10; ++c) out[(size_t)n * 10 + c] = z[c] - m - ls;
}

// ---------------------------------------------------------------------------
extern "C" void kernel_launch(void* const* d_in, const int* in_sizes, int n_in,
                              void* d_out, int out_size, void* d_ws, size_t ws_size,
                              hipStream_t stream) {
    const float* x     = (const float*)d_in[0];
    const float* ea    = (const float*)d_in[1];
    const int*   eidx  = (const int*)d_in[2];
    const float* W1    = (const float*)d_in[3];
    const float* b1    = (const float*)d_in[4];
    const float* We1   = (const float*)d_in[5];
    const float* be1   = (const float*)d_in[6];
    const float* root1 = (const float*)d_in[7];
    const float* bias1 = (const float*)d_in[8];
    const float* We2   = (const float*)d_in[9];
    const float* be2   = (const float*)d_in[10];
    const float* root2 = (const float*)d_in[11];
    const float* bias2 = (const float*)d_in[12];
    float* out = (float*)d_out;

    // workspace layout (float units, all 16B-aligned)
    float* ws = (float*)d_ws;
    ushort* h_bf = (ushort*)ws;                        // 1,280,000 us = 640,000 f
    ushort* B1t  = (ushort*)(ws + 640000);             // 147,456 us -> 73,728 f
    ushort* B2t  = (ushort*)(ws + 713728);             // 12,288 us -> 6,144 f
    ushort* G1t  = (ushort*)(ws + 719872);             // 10,240,000 us -> 5,120,000 f
    float* hrb1 = ws + 719872 + 5120000;               // 640,000
    float* hb1  = hrb1 + 640000;                       // 640,000
    float* agg1 = hb1  + 640000;                       // 640,000  (contiguous with agg2)
    float* agg2 = agg1 + 640000;                       // 100,000
    float* G2t  = agg2 + 100000;                       // 1,600,000
    float* hb2  = G2t  + 1600000;                      // 100,000
    float* hr2  = hb2  + 100000;                       // 100,000

    kA_prep<<<KA_B4, 256, 0, stream>>>(x, W1, b1, We1, root1, be1, We2, be2, root2,
                                       h_bf, B1t, B2t, agg1);
    k3_mfma<<<dim3(79, 18), 256, 0, stream>>>(h_bf, B1t, bias1, G1t, hrb1, hb1);
    k4_edge1<<<7500, 256, 0, stream>>>(ea, eidx, eidx + N_EDGES, G1t, hb1, agg1);
    k56_mfma<<<dim3(157, 3), 256, 0, stream>>>(agg1, hrb1, B2t, bias2, G2t, hb2, hr2);
    k7_edge2<<<1172, 256, 0, stream>>>(ea, eidx, eidx + N_EDGES, G2t, hb2, agg2);
    k8_logsoftmax<<<40, 256, 0, stream>>>(agg2, hr2, out);
}